// Round 6
// baseline (370.209 us; speedup 1.0000x reference)
//
#include <hip/hip_runtime.h>
#include <hip/hip_bf16.h>

#define BATCH 2
#define SEQ   2048
#define CH    1024
#define NH    16
#define HD    64
#define BHN   (BATCH*NH)   /* 32 */
#define SD    (SEQ*HD)     /* 131072 */

typedef short v8s __attribute__((ext_vector_type(8)));
typedef short v4s __attribute__((ext_vector_type(4)));
typedef float v4f __attribute__((ext_vector_type(4)));

#define SCHED0() __builtin_amdgcn_sched_barrier(0)

__device__ __forceinline__ short f2bf(float f) {
    unsigned u = __float_as_uint(f);
    u += 0x7fff + ((u >> 16) & 1);   // RNE; finite inputs
    return (short)(u >> 16);
}

// packed RNE: returns (bf16(a) | bf16(b)<<16) via v_cvt_pk_bf16_f32
__device__ __forceinline__ unsigned pk2bf(float a, float b) {
    __hip_bfloat162 h = __float22bfloat162_rn(make_float2(a, b));
    unsigned u;
    __builtin_memcpy(&u, &h, 4);
    return u;
}

// v_exp_f32 IS exp2 on AMDGCN (scores are pre-scaled by log2e in proj)
__device__ __forceinline__ float ex2(float x) {
    float r; asm("v_exp_f32 %0, %1" : "=v"(r) : "v"(x)); return r;
}

#if __has_builtin(__builtin_amdgcn_perm)
#define PERMB(a, b, s) __builtin_amdgcn_perm((a), (b), (s))
#else
__device__ __forceinline__ unsigned PERMB(unsigned a, unsigned b, unsigned s) {
    unsigned r = 0;
#pragma unroll
    for (int i = 0; i < 4; i++) {
        unsigned sb = (s >> (8 * i)) & 0xff, byte;
        if (sb >= 12) byte = (sb == 12) ? 0u : 0xffu;
        else if (sb < 4) byte = (b >> (8 * sb)) & 0xff;
        else byte = (a >> (8 * (sb - 4))) & 0xff;
        r |= byte << (8 * i);
    }
    return r;
}
#endif

__device__ __forceinline__ void gl_lds16(const short* g, short* l) {
    __builtin_amdgcn_global_load_lds(
        (const __attribute__((address_space(1))) void*)g,
        (__attribute__((address_space(3))) void*)l, 16, 0, 0);
}

// ---------------------------------------------------------------------------
// Fused fp32 -> bf16 cast for src / Wq / Wk / Wv / rel_k_table.
// ---------------------------------------------------------------------------
__global__ __launch_bounds__(256) void cast_all_kernel(
    const float* __restrict__ src, const float* __restrict__ wq,
    const float* __restrict__ wk, const float* __restrict__ wv,
    const float* __restrict__ rel,
    short* __restrict__ xb, short* __restrict__ wqb,
    short* __restrict__ wkb, short* __restrict__ wvb,
    short* __restrict__ relb)
{
    const int z = blockIdx.z;
    const float* s; short* d; int n4;
    switch (z) {
        case 0: s = src; d = xb;   n4 = 1048576; break;  // 4Mi elems
        case 1: s = wq;  d = wqb;  n4 = 262144;  break;
        case 2: s = wk;  d = wkb;  n4 = 262144;  break;
        case 3: s = wv;  d = wvb;  n4 = 262144;  break;
        default: s = rel; d = relb; n4 = 65520;  break;  // 4095*64/4
    }
    for (int i = blockIdx.x * 256 + threadIdx.x; i < n4; i += gridDim.x * 256) {
        float4 v = ((const float4*)s)[i];
        v4s o; o.x = f2bf(v.x); o.y = f2bf(v.y); o.z = f2bf(v.z); o.w = f2bf(v.w);
        ((v4s*)d)[i] = o;
    }
}

// ---------------------------------------------------------------------------
// bf16 MFMA projection GEMM: out[m][n] = sum_k X[m][k]*W[n][k] + bias[n]
// M=4096, N=K=1024. 128x128 tile, BK=32, global_load_lds width 16.
// z==0 (Q): result pre-scaled by 0.125*log2e (attn uses raw exp2).
// ---------------------------------------------------------------------------
__global__ __launch_bounds__(256, 3) void proj_mfma_kernel(
    const short* __restrict__ Xb,
    const short* __restrict__ Wqb, const short* __restrict__ Wkb,
    const short* __restrict__ Wvb,
    const float* __restrict__ bq, const float* __restrict__ bk,
    const float* __restrict__ bv,
    short* __restrict__ qo, short* __restrict__ ko, short* __restrict__ vo)
{
    const int z = blockIdx.z;
    const short* W    = (z == 0) ? Wqb : (z == 1) ? Wkb : Wvb;
    const float* bias = (z == 0) ? bq  : (z == 1) ? bk  : bv;
    short*       out  = (z == 0) ? qo  : (z == 1) ? ko  : vo;
    const float  osc  = (z == 0) ? 0.125f * 1.44269504088896f : 1.0f;

    const int m0 = blockIdx.x * 128;
    const int n0 = blockIdx.y * 128;
    const int tid  = threadIdx.x;
    const int w    = tid >> 6;
    const int lane = tid & 63;
    const int l15  = lane & 15;
    const int quad = lane >> 4;
    const int wm = w & 1, wn = w >> 1;

    __shared__ short Al[128 * 32];   // [row][k], stride 32 (no pad: glds)
    __shared__ short Bl[128 * 32];

    v4f acc[4][4];
#pragma unroll
    for (int i = 0; i < 4; i++)
#pragma unroll
        for (int j = 0; j < 4; j++) acc[i][j] = (v4f)(0.f);

    const int lr = lane >> 2;          // 0..15 row-within-slab
    const int lc = (lane & 3) * 8;     // k-offset

    for (int k0 = 0; k0 < 1024; k0 += 32) {
        __syncthreads();
#pragma unroll
        for (int l = 0; l < 2; l++) {
            const int slab = w * 32 + l * 16;
            gl_lds16(Xb + (size_t)(m0 + slab + lr) * 1024 + k0 + lc,
                     &Al[slab * 32]);
            gl_lds16(W + (size_t)(n0 + slab + lr) * 1024 + k0 + lc,
                     &Bl[slab * 32]);
        }
        __syncthreads();
        v8s af[4], bf[4];
#pragma unroll
        for (int mt = 0; mt < 4; mt++)
            af[mt] = *(const v8s*)&Al[(wm * 64 + mt * 16 + l15) * 32 + quad * 8];
#pragma unroll
        for (int nt = 0; nt < 4; nt++)
            bf[nt] = *(const v8s*)&Bl[(wn * 64 + nt * 16 + l15) * 32 + quad * 8];
#pragma unroll
        for (int mt = 0; mt < 4; mt++)
#pragma unroll
            for (int nt = 0; nt < 4; nt++)
                acc[mt][nt] = __builtin_amdgcn_mfma_f32_16x16x32_bf16(
                    af[mt], bf[nt], acc[mt][nt], 0, 0, 0);
    }

    float bv4[4];
#pragma unroll
    for (int nt = 0; nt < 4; nt++)
        bv4[nt] = bias[n0 + wn * 64 + nt * 16 + l15];
#pragma unroll
    for (int mt = 0; mt < 4; mt++)
#pragma unroll
        for (int rg = 0; rg < 4; rg++) {
            const int row = m0 + wm * 64 + mt * 16 + quad * 4 + rg;
#pragma unroll
            for (int nt = 0; nt < 4; nt++)
                out[(size_t)row * 1024 + n0 + wn * 64 + nt * 16 + l15] =
                    f2bf((acc[mt][nt][rg] + bv4[nt]) * osc);
        }
}

// ---------------------------------------------------------------------------
// V transpose per (b,h): vt[bh][d][.] = v[bh][.][d].  64x64 LDS tiles.
// Columns within each 64-wide t-group are stored PERMUTED:
//   position p holds t(p) = (p>>2) + 16*(p&3)   (inverse: p = (t&15)*4 + t>>4)
// so the attention kernel's P-tile can be written with packed b64 stores AND
// V B-fragments are contiguous b128 global reads (positions quad*8..+7).
// ---------------------------------------------------------------------------
__global__ __launch_bounds__(256) void vtrans_kernel(
    const short* __restrict__ v, short* __restrict__ vt)
{
    const int bh = blockIdx.y;
    const int t0 = blockIdx.x * 64;
    const int r = threadIdx.x >> 3;          // 0..31
    const int c = (threadIdx.x & 7) * 8;     // 0..56

    __shared__ short T[64][72];
    *(v8s*)&T[r][c] =
        *(const v8s*)(v + (size_t)bh * SD + (size_t)(t0 + r) * HD + c);
    *(v8s*)&T[r + 32][c] =
        *(const v8s*)(v + (size_t)bh * SD + (size_t)(t0 + r + 32) * HD + c);
    __syncthreads();
    v8s o0, o1;
#pragma unroll
    for (int e = 0; e < 8; e++) {
        const int t = 2 * (threadIdx.x & 7) + (e >> 2) + 16 * (e & 3);
        o0[e] = T[t][r];
        o1[e] = T[t][r + 32];
    }
    *(v8s*)(vt + (size_t)bh * SD + (size_t)r * SEQ + t0 + c) = o0;
    *(v8s*)(vt + (size_t)bh * SD + (size_t)(r + 32) * SEQ + t0 + c) = o1;
}

// ---------------------------------------------------------------------------
// MFMA flash attention with relative-position scores (bf16 inputs; q tensor
// pre-scaled by log2e/8 in the projection; probabilities via raw v_exp_f32).
//   score[i][t]*log2e = qs[i]·k[t] + qrs[i]·rel[t-i+2047]
//
// R16 (register-direct operand feeds; zero barriers): R15's flat result
// exonerated drain latency — the binder was the LDS pipe, where all 4 waves
// read IDENTICAL K/V/rel fragments (kaddr independent of w => 4x redundant
// LDS reads). K/V^T/rel are L2-resident per XCD (bh-major grid, ~2.5MB<4MB),
// and every fragment is a contiguous b128 in global (vtrans pre-permutes
// V^T positions). So: load fragments global->VGPR directly with one-phase-
// ahead prefetch (consume-then-reload: kfp/vfp/rfp single generation).
//  * LDS holds ONLY Pb (16KB); LDS instr/wave-iter 64 -> 36.
//  * All loads register-destined -> compiler-managed vmcnt; NO barriers
//    (Pb is wave-private, bpermute intra-wave) — waves free-run; setprio
//    arbitrates MFMA clusters.
//  * sched_barrier(0) pins keep prefetch issue at phase boundaries
//    (rfp after PHASE1 to avoid overlapping racc liveness -> spills).
//  * Delayed-PV retained: PV(t-1) runs between PHASE1(t) and PHASE2(t).
// ---------------------------------------------------------------------------
__global__ __launch_bounds__(256, 2) void attn_mfma_kernel(
    const short* __restrict__ qb, const short* __restrict__ kb,
    const short* __restrict__ vtb, const short* __restrict__ relb,
    float* __restrict__ out)
{
    const int tid  = threadIdx.x;
    const int w    = tid >> 6;               // 0..3
    const int lane = tid & 63;
    const int l15  = lane & 15;
    const int quad = lane >> 4;
    const int bh = blockIdx.x, b = bh >> 4, h = bh & 15;
    const int s0 = blockIdx.y * 128;
    const int i0 = w * 32;                   // wave's 32-row slab

    __shared__ short Pb[4][2][16][64];   // per-wave/mt P (bf16, perm cols, swz)

    // ---- loop-invariant q fragments (both views, both m-tiles) ----
    v8s qc_f[2][2], qr_f[2][2];
#pragma unroll
    for (int mt = 0; mt < 2; mt++)
#pragma unroll
    for (int kh = 0; kh < 2; kh++) {
        const int row = s0 + i0 + mt * 16 + l15;
        qc_f[mt][kh] = *(const v8s*)(qb + (size_t)bh * SD +
                                     (size_t)row * HD + kh * 32 + quad * 8);
        qr_f[mt][kh] = *(const v8s*)(qb + (size_t)row * (BHN * HD) +
                                     bh * HD + kh * 32 + quad * 8);
    }

    // ---- loop-invariant gather selectors (v_perm; 0x0c = zero byte) ----
    int      slv4[4];
    unsigned selA[4], selB[4], pwoff[4];
#pragma unroll
    for (int rg = 0; rg < 4; rg++) {
        const int ii = quad * 4 + rg;
        const int e  = l15 + 15 - ii;          // [0,30]
        const bool lo = (e < 16);
        slv4[rg] = (quad * 16 + (e & 15)) << 2;
        selA[rg] = lo ? 0x05040c0cu : 0x07060c0cu;   // lo16<<16 : hi16
        selB[rg] = lo ? 0x07060c0cu : 0x01000c0cu;   // S0 hi16 : S1 lo16<<16
        pwoff[rg] = (unsigned)(w * 4096 + ii * 128 +
                    ((((l15 >> 1) ^ (ii & 7)) << 4) + ((l15 & 1) << 3)));
    }
    const int paddr0 = (l15 << 7) + ((quad ^ (l15 & 7)) << 4);  // Pb read

    // ---- carried per-lane global element offsets (shorts) ----
    unsigned koff = (unsigned)bh * SD + (unsigned)l15 * HD + quad * 8;   // K[0]
    unsigned voff[4];
#pragma unroll
    for (int nt = 0; nt < 4; nt++)
        voff[nt] = (unsigned)bh * SD + (unsigned)(nt * 16 + l15) * SEQ + quad * 8;
    unsigned roffs[6];
#pragma unroll
    for (int st = 0; st < 6; st++)
        roffs[st] = (unsigned)(2032 - s0 - i0 - 16 + st * 16 + l15) * HD + quad * 8;
    const unsigned RMAX = 4094u * HD;        // clamp (garbage rows unused)

    // ---- prefetched operand fragments ----
    v8s kfp[2][4], vfp[2][4], rfp[6][2];

    auto LOAD_K = [&]() {                    // fills kfp with tile at koff
#pragma unroll
        for (int kh = 0; kh < 2; kh++)
#pragma unroll
            for (int nt = 0; nt < 4; nt++)
                kfp[kh][nt] = *(const v8s*)(kb + koff + nt * 1024 + kh * 32);
        koff += 4096;
    };
    auto LOAD_V = [&]() {
#pragma unroll
        for (int kh = 0; kh < 2; kh++)
#pragma unroll
            for (int nt = 0; nt < 4; nt++)
                vfp[kh][nt] = *(const v8s*)(vtb + voff[nt] + kh * 32);
#pragma unroll
        for (int nt = 0; nt < 4; nt++) voff[nt] += 64;
    };
    auto LOAD_R = [&]() {
#pragma unroll
        for (int st = 0; st < 6; st++) {
            const unsigned c = roffs[st] < RMAX ? roffs[st] : RMAX;
#pragma unroll
            for (int kh = 0; kh < 2; kh++)
                rfp[st][kh] = *(const v8s*)(relb + c + kh * 32);
            roffs[st] += 4096;
        }
    };

    v4f o_acc[2][4];
#pragma unroll
    for (int mt = 0; mt < 2; mt++)
#pragma unroll
        for (int nt = 0; nt < 4; nt++) o_acc[mt][nt] = (v4f)(0.f);
    float lpart[2][4] = {{0.f,0.f,0.f,0.f},{0.f,0.f,0.f,0.f}};

    const v4f vz = (v4f)(0.f);               // shared zero C-operand

    v4f cacc[2][4], racc[2][5];
    unsigned g01[2][4], g23[2][4], g4v[2][4];

    auto QK = [&]() {                        // consumes kfp, rfp
        __builtin_amdgcn_s_setprio(1);
#pragma unroll
        for (int mt = 0; mt < 2; mt++)
#pragma unroll
            for (int nt = 0; nt < 4; nt++)
                cacc[mt][nt] = __builtin_amdgcn_mfma_f32_16x16x32_bf16(
                    qc_f[mt][0], kfp[0][nt], vz, 0, 0, 0);
#pragma unroll
        for (int jt = 0; jt < 5; jt++)
            racc[0][jt] = __builtin_amdgcn_mfma_f32_16x16x32_bf16(
                qr_f[0][0], rfp[jt + 1][0], vz, 0, 0, 0);
#pragma unroll
        for (int jt = 0; jt < 5; jt++)
            racc[1][jt] = __builtin_amdgcn_mfma_f32_16x16x32_bf16(
                qr_f[1][0], rfp[jt][0], vz, 0, 0, 0);
#pragma unroll
        for (int mt = 0; mt < 2; mt++)
#pragma unroll
            for (int nt = 0; nt < 4; nt++)
                cacc[mt][nt] = __builtin_amdgcn_mfma_f32_16x16x32_bf16(
                    qc_f[mt][1], kfp[1][nt], cacc[mt][nt], 0, 0, 0);
#pragma unroll
        for (int jt = 0; jt < 5; jt++)
            racc[0][jt] = __builtin_amdgcn_mfma_f32_16x16x32_bf16(
                qr_f[0][1], rfp[jt + 1][1], racc[0][jt], 0, 0, 0);
#pragma unroll
        for (int jt = 0; jt < 5; jt++)
            racc[1][jt] = __builtin_amdgcn_mfma_f32_16x16x32_bf16(
                qr_f[1][1], rfp[jt][1], racc[1][jt], 0, 0, 0);
        __builtin_amdgcn_s_setprio(0);
    };

    auto PHASE1 = [&]() {                    // pack + 24 bpermutes (racc dies)
#pragma unroll
        for (int mt = 0; mt < 2; mt++)
#pragma unroll
        for (int rg = 0; rg < 4; rg++) {
            unsigned p01 = pk2bf(racc[mt][0][rg], racc[mt][1][rg]);
            unsigned p23 = pk2bf(racc[mt][2][rg], racc[mt][3][rg]);
            unsigned p4  = pk2bf(racc[mt][4][rg], racc[mt][4][rg]);
            g01[mt][rg] = (unsigned)__builtin_amdgcn_ds_bpermute(slv4[rg], (int)p01);
            g23[mt][rg] = (unsigned)__builtin_amdgcn_ds_bpermute(slv4[rg], (int)p23);
            g4v[mt][rg] = (unsigned)__builtin_amdgcn_ds_bpermute(slv4[rg], (int)p4);
        }
    };

    auto PHASE2 = [&]() {                    // skew-select + exp2 + Pb writes
#pragma unroll
        for (int mt = 0; mt < 2; mt++)
#pragma unroll
        for (int rg = 0; rg < 4; rg++) {
            const unsigned a01 = g01[mt][rg], a23 = g23[mt][rg], a4 = g4v[mt][rg];
            unsigned pb0 = PERMB(a01, a01, selA[rg]);
            unsigned pb1 = PERMB(a01, a23, selB[rg]);
            unsigned pb2 = PERMB(a23, a23, selA[rg]);
            unsigned pb3 = PERMB(a23, a4,  selB[rg]);
            float p0 = ex2(cacc[mt][0][rg] + __uint_as_float(pb0));
            float p1 = ex2(cacc[mt][1][rg] + __uint_as_float(pb1));
            float p2 = ex2(cacc[mt][2][rg] + __uint_as_float(pb2));
            float p3 = ex2(cacc[mt][3][rg] + __uint_as_float(pb3));
            lpart[mt][rg] += (p0 + p1) + (p2 + p3);
            *(uint2*)((char*)Pb + pwoff[rg] + mt * 2048) =
                make_uint2(pk2bf(p0, p1), pk2bf(p2, p3));
        }
    };

    auto PV = [&]() {                        // consumes vfp; Pb from last PHASE2
        const char* pbW = (const char*)Pb + w * 4096;
#pragma unroll
        for (int kh = 0; kh < 2; kh++) {
            v8s pa0 = *(const v8s*)(pbW + (paddr0 ^ (kh << 6)));
            v8s pa1 = *(const v8s*)(pbW + 2048 + (paddr0 ^ (kh << 6)));
            __builtin_amdgcn_s_setprio(1);
#pragma unroll
            for (int nt = 0; nt < 4; nt++)
                o_acc[0][nt] = __builtin_amdgcn_mfma_f32_16x16x32_bf16(
                    pa0, vfp[kh][nt], o_acc[0][nt], 0, 0, 0);
#pragma unroll
            for (int nt = 0; nt < 4; nt++)
                o_acc[1][nt] = __builtin_amdgcn_mfma_f32_16x16x32_bf16(
                    pa1, vfp[kh][nt], o_acc[1][nt], 0, 0, 0);
            __builtin_amdgcn_s_setprio(0);
        }
    };

    // ================= prologue: fill all prefetch registers =================
    LOAD_K();                        // K[0]
    LOAD_R();                        // rel(0)
    LOAD_V();                        // V[0]

    // ================= tile 0 (no PV yet) =================
    QK();                            // consumes K[0], rel(0)
    SCHED0(); LOAD_K(); SCHED0();    // K[1]
    PHASE1();
    SCHED0(); LOAD_R(); SCHED0();    // rel(1)
    PHASE2();

    // ================= main loop (31 iterations) =================
    for (int t0 = 64; t0 < SEQ; t0 += 64) {
        QK();                        // tile t: consumes kfp, rfp
        SCHED0(); LOAD_K(); SCHED0();// K[t+1]
        PHASE1();
        SCHED0(); LOAD_R(); SCHED0();// rel(t+1)
        PV();                        // PV(t-1): consumes vfp = V[t-1]
        SCHED0(); LOAD_V(); SCHED0();// V[t]
        PHASE2();
    }
    PV();                            // PV(last): vfp = V[31]

    // ---- epilogue: row-sum reductions, then normalized stores ----
#pragma unroll
    for (int mt = 0; mt < 2; mt++)
#pragma unroll
    for (int rg = 0; rg < 4; rg++) {
        float rs = lpart[mt][rg];
#pragma unroll
        for (int off = 1; off < 16; off <<= 1)
            rs += __shfl_xor(rs, off);
        const float inv = 1.f / rs;
        const int row = s0 + i0 + mt * 16 + quad * 4 + rg;
        const size_t base = ((size_t)b * SEQ + row) * CH + h * HD;
#pragma unroll
        for (int nt = 0; nt < 4; nt++)
            out[base + nt * 16 + l15] = o_acc[mt][nt][rg] * inv;
    }
}

// ---------------------------------------------------------------------------
extern "C" void kernel_launch(void* const* d_in, const int* in_sizes, int n_in,
                              void* d_out, int out_size, void* d_ws, size_t ws_size,
                              hipStream_t stream)
{
    const float* src  = (const float*)d_in[0];
    const float* Wq   = (const float*)d_in[1];
    const float* bq   = (const float*)d_in[2];
    const float* Wk   = (const float*)d_in[3];
    const float* bk   = (const float*)d_in[4];
    const float* Wv   = (const float*)d_in[5];
    const float* bv   = (const float*)d_in[6];
    const float* relk = (const float*)d_in[7];
    float* out = (float*)d_out;

    const size_t nQKV = (size_t)BATCH * SEQ * CH;      // 4 Mi elements
    const size_t nW   = (size_t)CH * CH;               // 1 Mi
    short* qb   = (short*)d_ws;
    short* kb   = qb + nQKV;
    short* vb   = kb + nQKV;
    short* vtb  = vb + nQKV;
    short* xb   = vtb + nQKV;
    short* wqb  = xb + nQKV;
    short* wkb  = wqb + nW;
    short* wvb  = wkb + nW;
    short* relb = wvb + nW;                            // 4095*64 bf16

    cast_all_kernel<<<dim3(512, 1, 5), 256, 0, stream>>>(
        src, Wq, Wk, Wv, relk, xb, wqb, wkb, wvb, relb);

    dim3 gProj(4096 / 128, 1024 / 128, 3);             // (32, 8, 3): x = m-panel
    proj_mfma_kernel<<<gProj, 256, 0, stream>>>(
        xb, wqb, wkb, wvb, bq, bk, bv, qb, kb, vb);

    dim3 gVt(SEQ / 64, BHN);                           // (32, 32)
    vtrans_kernel<<<gVt, 256, 0, stream>>>(vb, vtb);

    dim3 gAttn(BHN, SEQ / 128);                        // (32, 16): x = bh
    attn_mfma_kernel<<<gAttn, 256, 0, stream>>>(qb, kb, vtb, relb, out);
}

// Round 8
// 203.447 us; speedup vs baseline: 1.8197x; 1.8197x over previous
//
#include <hip/hip_runtime.h>
#include <hip/hip_bf16.h>

#define BATCH 2
#define SEQ   2048
#define CH    1024
#define NH    16
#define HD    64
#define BHN   (BATCH*NH)   /* 32 */
#define SD    (SEQ*HD)     /* 131072 */

typedef short v8s __attribute__((ext_vector_type(8)));
typedef short v4s __attribute__((ext_vector_type(4)));
typedef float v4f __attribute__((ext_vector_type(4)));

#define VMCNT2() asm volatile("s_waitcnt vmcnt(2)" ::: "memory")
#define VMCNT0() asm volatile("s_waitcnt vmcnt(0)" ::: "memory")
#define SBAR()  do { __builtin_amdgcn_sched_barrier(0); \
                     __builtin_amdgcn_s_barrier();      \
                     __builtin_amdgcn_sched_barrier(0); } while (0)

__device__ __forceinline__ short f2bf(float f) {
    unsigned u = __float_as_uint(f);
    u += 0x7fff + ((u >> 16) & 1);   // RNE; finite inputs
    return (short)(u >> 16);
}

// packed RNE: returns (bf16(a) | bf16(b)<<16) via v_cvt_pk_bf16_f32
__device__ __forceinline__ unsigned pk2bf(float a, float b) {
    __hip_bfloat162 h = __float22bfloat162_rn(make_float2(a, b));
    unsigned u;
    __builtin_memcpy(&u, &h, 4);
    return u;
}

// v_exp_f32 IS exp2 on AMDGCN (scores are pre-scaled by log2e in proj)
__device__ __forceinline__ float ex2(float x) {
    float r; asm("v_exp_f32 %0, %1" : "=v"(r) : "v"(x)); return r;
}

__device__ __forceinline__ void gl_lds16(const short* g, short* l) {
    __builtin_amdgcn_global_load_lds(
        (const __attribute__((address_space(1))) void*)g,
        (__attribute__((address_space(3))) void*)l, 16, 0, 0);
}

// ---------------------------------------------------------------------------
// Fused fp32 -> bf16 cast for src / Wq / Wk / Wv / rel_k_table.
// ---------------------------------------------------------------------------
__global__ __launch_bounds__(256) void cast_all_kernel(
    const float* __restrict__ src, const float* __restrict__ wq,
    const float* __restrict__ wk, const float* __restrict__ wv,
    const float* __restrict__ rel,
    short* __restrict__ xb, short* __restrict__ wqb,
    short* __restrict__ wkb, short* __restrict__ wvb,
    short* __restrict__ relb)
{
    const int z = blockIdx.z;
    const float* s; short* d; int n4;
    switch (z) {
        case 0: s = src; d = xb;   n4 = 1048576; break;  // 4Mi elems
        case 1: s = wq;  d = wqb;  n4 = 262144;  break;
        case 2: s = wk;  d = wkb;  n4 = 262144;  break;
        case 3: s = wv;  d = wvb;  n4 = 262144;  break;
        default: s = rel; d = relb; n4 = 65520;  break;  // 4095*64/4
    }
    for (int i = blockIdx.x * 256 + threadIdx.x; i < n4; i += gridDim.x * 256) {
        float4 v = ((const float4*)s)[i];
        v4s o; o.x = f2bf(v.x); o.y = f2bf(v.y); o.z = f2bf(v.z); o.w = f2bf(v.w);
        ((v4s*)d)[i] = o;
    }
}

// ---------------------------------------------------------------------------
// bf16 MFMA projection GEMM: out[m][n] = sum_k X[m][k]*W[n][k] + bias[n]
// M=4096, N=K=1024. 128x128 tile, global_load_lds width 16.
// R17: BK=64 (half the barriers) + XOR-swizzled [128][64] LDS tiles:
// chunk c of row r holds src chunk c^(r&7) -> ds_read_b128 fragments are
// 2-way bank aliased (free) instead of 8-way. 32KB LDS -> 3 blocks/CU.
// z==0 (Q): result pre-scaled by 0.125*log2e (attn uses raw exp2).
// ---------------------------------------------------------------------------
__global__ __launch_bounds__(256, 3) void proj_mfma_kernel(
    const short* __restrict__ Xb,
    const short* __restrict__ Wqb, const short* __restrict__ Wkb,
    const short* __restrict__ Wvb,
    const float* __restrict__ bq, const float* __restrict__ bk,
    const float* __restrict__ bv,
    short* __restrict__ qo, short* __restrict__ ko, short* __restrict__ vo)
{
    const int z = blockIdx.z;
    const short* W    = (z == 0) ? Wqb : (z == 1) ? Wkb : Wvb;
    const float* bias = (z == 0) ? bq  : (z == 1) ? bk  : bv;
    short*       out  = (z == 0) ? qo  : (z == 1) ? ko  : vo;
    const float  osc  = (z == 0) ? 0.125f * 1.44269504088896f : 1.0f;

    const int m0 = blockIdx.x * 128;
    const int n0 = blockIdx.y * 128;
    const int tid  = threadIdx.x;
    const int w    = tid >> 6;
    const int lane = tid & 63;
    const int l15  = lane & 15;
    const int quad = lane >> 4;
    const int wm = w & 1, wn = w >> 1;

    __shared__ short Al[128 * 64];   // [row][64], XOR-swizzled chunks
    __shared__ short Bl[128 * 64];

    v4f acc[4][4];
#pragma unroll
    for (int i = 0; i < 4; i++)
#pragma unroll
        for (int j = 0; j < 4; j++) acc[i][j] = (v4f)(0.f);

    // staging: 256 threads x 4 issues cover 128 rows x 64 cols
    const int srow = tid >> 3;                     // 0..31
    const int scol = ((tid & 7) ^ (srow & 7)) * 8; // pre-swizzled src chunk

    // fragment read offsets (shorts), both kk halves
    int aoff[2][4], boff[2][4];
#pragma unroll
    for (int kk = 0; kk < 2; kk++) {
#pragma unroll
        for (int mt = 0; mt < 4; mt++) {
            const int ra = wm * 64 + mt * 16 + l15;
            aoff[kk][mt] = ra * 64 + ((((kk << 2) | quad) ^ (ra & 7)) << 3);
        }
#pragma unroll
        for (int nt = 0; nt < 4; nt++) {
            const int rb = wn * 64 + nt * 16 + l15;
            boff[kk][nt] = rb * 64 + ((((kk << 2) | quad) ^ (rb & 7)) << 3);
        }
    }

    for (int k0 = 0; k0 < 1024; k0 += 64) {
        __syncthreads();
#pragma unroll
        for (int j = 0; j < 4; j++) {
            gl_lds16(Xb + (size_t)(m0 + j * 32 + srow) * 1024 + k0 + scol,
                     &Al[(j * 32 + w * 8) * 64]);
            gl_lds16(W + (size_t)(n0 + j * 32 + srow) * 1024 + k0 + scol,
                     &Bl[(j * 32 + w * 8) * 64]);
        }
        __syncthreads();
#pragma unroll
        for (int kk = 0; kk < 2; kk++) {
            v8s af[4], bf4[4];
#pragma unroll
            for (int mt = 0; mt < 4; mt++)
                af[mt] = *(const v8s*)&Al[aoff[kk][mt]];
#pragma unroll
            for (int nt = 0; nt < 4; nt++)
                bf4[nt] = *(const v8s*)&Bl[boff[kk][nt]];
#pragma unroll
            for (int mt = 0; mt < 4; mt++)
#pragma unroll
                for (int nt = 0; nt < 4; nt++)
                    acc[mt][nt] = __builtin_amdgcn_mfma_f32_16x16x32_bf16(
                        af[mt], bf4[nt], acc[mt][nt], 0, 0, 0);
        }
    }

    float bv4[4];
#pragma unroll
    for (int nt = 0; nt < 4; nt++)
        bv4[nt] = bias[n0 + wn * 64 + nt * 16 + l15];
#pragma unroll
    for (int mt = 0; mt < 4; mt++)
#pragma unroll
        for (int rg = 0; rg < 4; rg++) {
            const int row = m0 + wm * 64 + mt * 16 + quad * 4 + rg;
#pragma unroll
            for (int nt = 0; nt < 4; nt++)
                out[(size_t)row * 1024 + n0 + wn * 64 + nt * 16 + l15] =
                    f2bf((acc[mt][nt][rg] + bv4[nt]) * osc);
        }
}

// ---------------------------------------------------------------------------
// V transpose per (b,h): vt[bh][d][.] = v[bh][.][d].  64x64 LDS tiles.
// Columns within each 64-wide t-group are stored PERMUTED:
//   position p holds t(p) = (p>>2) + 16*(p&3)   (inverse: p = (t&15)*4 + t>>4)
// so the attention kernel's P-tile can be written with packed b64 stores.
// ---------------------------------------------------------------------------
__global__ __launch_bounds__(256) void vtrans_kernel(
    const short* __restrict__ v, short* __restrict__ vt)
{
    const int bh = blockIdx.y;
    const int t0 = blockIdx.x * 64;
    const int r = threadIdx.x >> 3;          // 0..31
    const int c = (threadIdx.x & 7) * 8;     // 0..56

    __shared__ short T[64][72];
    *(v8s*)&T[r][c] =
        *(const v8s*)(v + (size_t)bh * SD + (size_t)(t0 + r) * HD + c);
    *(v8s*)&T[r + 32][c] =
        *(const v8s*)(v + (size_t)bh * SD + (size_t)(t0 + r + 32) * HD + c);
    __syncthreads();
    v8s o0, o1;
#pragma unroll
    for (int e = 0; e < 8; e++) {
        const int t = 2 * (threadIdx.x & 7) + (e >> 2) + 16 * (e & 3);
        o0[e] = T[t][r];
        o1[e] = T[t][r + 32];
    }
    *(v8s*)(vt + (size_t)bh * SD + (size_t)r * SEQ + t0 + c) = o0;
    *(v8s*)(vt + (size_t)bh * SD + (size_t)(r + 32) * SEQ + t0 + c) = o1;
}

// ---------------------------------------------------------------------------
// MFMA flash attention with relative-position scores (bf16 inputs; q tensor
// pre-scaled by log2e/8 in the projection; probabilities via raw v_exp_f32).
//   score[i][t]*log2e = qs[i]·k[t] + qrs[i]·rel[t-i+2047]
//
// R17 = R15 structure (101us, known good; R16 reg-direct reverted) + the
// source-side pack-selection gather:
//   lo-dests (e<16) pull only from source lanes s>=15-ii; hi-dests from
//   s<=14-ii (disjoint). Each source lane pre-selects its published pack:
//   q1 = slo ? pk(r0,r1) : pk(r1,r2);  q2 = slo ? pk(r2,r3) : pk(r3,r4)
//   -> TWO bpermutes per (mt,rg) instead of three, and the dest-side
//   extraction is uniform (g<<16 / g&0xffff0000) — PERMB + selA/selB gone.
// LDS ops/wave-iter 64 -> 56.
// LDS: 16K(K) + 16K(V) + 32K(rel ring) + 16K(Pb) = 80 KB -> 2 blocks/CU.
// ---------------------------------------------------------------------------
__global__ __launch_bounds__(256, 2) void attn_mfma_kernel(
    const short* __restrict__ qb, const short* __restrict__ kb,
    const short* __restrict__ vtb, const short* __restrict__ relb,
    float* __restrict__ out)
{
    const int tid  = threadIdx.x;
    const int w    = tid >> 6;               // 0..3
    const int lane = tid & 63;
    const int l15  = lane & 15;
    const int quad = lane >> 4;
    const int bh = blockIdx.x, b = bh >> 4, h = bh & 15;
    const int s0 = blockIdx.y * 128;
    const int i0 = w * 32;                   // wave's 32-row slab

    __shared__ short Kl[2][64][64];      // key tile, dbuf, XOR-swizzled
    __shared__ short Vl[2][64][64];      // V^T tile, dbuf, XOR-swizzled (+perm cols)
    __shared__ short Rl[256][64];        // rel ring, XOR-swizzled
    __shared__ short Pb[4][2][16][64];   // per-wave/mt P (bf16, perm cols, swz)

    // ---- loop-invariant q fragments (both views, both m-tiles) ----
    v8s qc_f[2][2], qr_f[2][2];
#pragma unroll
    for (int mt = 0; mt < 2; mt++)
#pragma unroll
    for (int kh = 0; kh < 2; kh++) {
        const int row = s0 + i0 + mt * 16 + l15;
        qc_f[mt][kh] = *(const v8s*)(qb + (size_t)bh * SD +
                                     (size_t)row * HD + kh * 32 + quad * 8);
        qr_f[mt][kh] = *(const v8s*)(qb + (size_t)row * (BHN * HD) +
                                     bh * HD + kh * 32 + quad * 8);
    }

    // ---- loop-invariant gather selectors ----
    int  slv4[4];
    bool slo[4];
    unsigned pwoff[4];
#pragma unroll
    for (int rg = 0; rg < 4; rg++) {
        const int ii = quad * 4 + rg;
        const int e  = l15 + 15 - ii;          // [0,30]
        slv4[rg] = (quad * 16 + (e & 15)) << 2;
        slo[rg]  = (l15 >= 15 - ii);           // source-side class
        pwoff[rg] = (unsigned)(w * 4096 + ii * 128 +
                    ((((l15 >> 1) ^ (ii & 7)) << 4) + ((l15 & 1) << 3)));
    }

    // ---- loop-invariant LDS read byte-offsets ----
    const int swz = (quad ^ (l15 & 7)) << 4;
    int kaddr[2][4];
#pragma unroll
    for (int kh = 0; kh < 2; kh++) {
        const int x = kh << 6;
#pragma unroll
        for (int nt = 0; nt < 4; nt++)
            kaddr[kh][nt] = (((nt * 16 + l15) << 7) + swz) ^ x;
    }
    const int paddr0 = (l15 << 7) + swz;       // within one 2KB Pb m-tile

    // ---- rel strip read byte-offsets (6 tiles; m1 uses 0..4, m0 uses 1..5) ----
    const int Bq = 1920 - s0;                  // min logical rel row for block
    int raddr[6];
#pragma unroll
    for (int st = 0; st < 6; st++) {
        const int lg = 2032 - s0 - i0 - 16 + st * 16 + l15;  // m1 frame @ t0=0
        raddr[st] = ((lg & 255) << 7) + ((quad ^ (lg & 7)) << 4);
    }

    // ---- staging geometry: 256 threads x2 issues cover one 64x64 tile ----
    const int strow = tid >> 3;                            // 0..31
    const int stc   = ((tid & 7) ^ (strow & 7)) * 8;       // swizzled src col
    const short* ksrc = kb  + (size_t)bh * SD + (size_t)strow * HD  + stc;
    const short* vsrc = vtb + (size_t)bh * SD + (size_t)strow * SEQ + stc;

    // ---- prologue staging: rel window [Bq, Bq+192) + K/V tile 0 ----
#pragma unroll
    for (int g = 0; g < 3; g++) {
        const int r0 = Bq + g * 64 + strow;
        const int ra = r0 < 4094 ? r0 : 4094;
        const int rb2 = (r0 + 32) < 4094 ? (r0 + 32) : 4094;
        const unsigned sl = (unsigned)((Bq + g * 64 + w * 8) & 255) << 7;
        gl_lds16(relb + (size_t)ra * HD + stc, (short*)((char*)Rl + sl));
        gl_lds16(relb + (size_t)rb2 * HD + stc, (short*)((char*)Rl + sl + 4096));
    }
    gl_lds16(ksrc,              &Kl[0][w * 8][0]);
    gl_lds16(ksrc + 32 * HD,    &Kl[0][32 + w * 8][0]);
    gl_lds16(vsrc,              &Vl[0][w * 8][0]);
    gl_lds16(vsrc + 32 * SEQ,   &Vl[0][32 + w * 8][0]);

    // ---- carried staging pointers ----
    const short* kp = ksrc + 4096;             // tile 1 (64 keys * HD)
    const short* vp = vsrc + 64;
    const char*  relbp = (const char*)relb + stc * 2;
    unsigned roff = (unsigned)(Bq + 192 + strow) * 128;  // byte row offset
    const unsigned ROMAX = 4094u * 128;
    unsigned rlds = (unsigned)((Bq + 192 + w * 8) & 255) << 7;

    v4f o_acc[2][4];
#pragma unroll
    for (int mt = 0; mt < 2; mt++)
#pragma unroll
        for (int nt = 0; nt < 4; nt++) o_acc[mt][nt] = (v4f)(0.f);
    float lpart[2][4] = {{0.f,0.f,0.f,0.f},{0.f,0.f,0.f,0.f}};

    const v4f vz = (v4f)(0.f);               // shared zero C-operand

    // ---- pipeline state (shared by phase lambdas) ----
    v4f cacc[2][4], racc[2][5];
    unsigned g1v[2][4], g2v[2][4];

    auto STAGE_K = [&](int dst) {            // K[next] + rel ring advance
        short* kd = &Kl[0][w * 8][0] + (dst << 12);
        gl_lds16(kp,            kd);
        gl_lds16(kp + 32 * HD,  kd + 32 * 64);
        unsigned rc0 = roff < ROMAX ? roff : ROMAX;
        unsigned rc1 = (roff + 4096) < ROMAX ? (roff + 4096) : ROMAX;
        gl_lds16((const short*)(relbp + rc0), (short*)((char*)Rl + rlds));
        gl_lds16((const short*)(relbp + rc1), (short*)((char*)Rl + rlds + 4096));
        kp += 4096; roff += 8192; rlds = (rlds + 8192) & 32767;
    };

    auto STAGE_V = [&](int dst) {            // V[next]
        short* vd = &Vl[0][w * 8][0] + (dst << 12);
        gl_lds16(vp,            vd);
        gl_lds16(vp + 32 * SEQ, vd + 32 * 64);
        vp += 64;
    };

    auto QK = [&](int cur) {
        const char* kbase = (const char*)Kl + cur * 8192;
        const char* rbase = (const char*)Rl;
        // --- kh = 0: MFMA with zero C (no acc init) ---
        {
            v8s kf[4], rfj[6];
#pragma unroll
            for (int nt = 0; nt < 4; nt++)
                kf[nt] = *(const v8s*)(kbase + kaddr[0][nt]);
#pragma unroll
            for (int st = 0; st < 6; st++)
                rfj[st] = *(const v8s*)(rbase + raddr[st]);
            __builtin_amdgcn_s_setprio(1);
#pragma unroll
            for (int mt = 0; mt < 2; mt++)
#pragma unroll
                for (int nt = 0; nt < 4; nt++)
                    cacc[mt][nt] = __builtin_amdgcn_mfma_f32_16x16x32_bf16(
                        qc_f[mt][0], kf[nt], vz, 0, 0, 0);
#pragma unroll
            for (int jt = 0; jt < 5; jt++)
                racc[0][jt] = __builtin_amdgcn_mfma_f32_16x16x32_bf16(
                    qr_f[0][0], rfj[jt + 1], vz, 0, 0, 0);
#pragma unroll
            for (int jt = 0; jt < 5; jt++)
                racc[1][jt] = __builtin_amdgcn_mfma_f32_16x16x32_bf16(
                    qr_f[1][0], rfj[jt], vz, 0, 0, 0);
            __builtin_amdgcn_s_setprio(0);
        }
        // --- kh = 1: accumulate ---
        {
            v8s kf[4], rfj[6];
#pragma unroll
            for (int nt = 0; nt < 4; nt++)
                kf[nt] = *(const v8s*)(kbase + kaddr[1][nt]);
#pragma unroll
            for (int st = 0; st < 6; st++)
                rfj[st] = *(const v8s*)(rbase + (raddr[st] ^ 64));
            __builtin_amdgcn_s_setprio(1);
#pragma unroll
            for (int mt = 0; mt < 2; mt++)
#pragma unroll
                for (int nt = 0; nt < 4; nt++)
                    cacc[mt][nt] = __builtin_amdgcn_mfma_f32_16x16x32_bf16(
                        qc_f[mt][1], kf[nt], cacc[mt][nt], 0, 0, 0);
#pragma unroll
            for (int jt = 0; jt < 5; jt++)
                racc[0][jt] = __builtin_amdgcn_mfma_f32_16x16x32_bf16(
                    qr_f[0][1], rfj[jt + 1], racc[0][jt], 0, 0, 0);
#pragma unroll
            for (int jt = 0; jt < 5; jt++)
                racc[1][jt] = __builtin_amdgcn_mfma_f32_16x16x32_bf16(
                    qr_f[1][1], rfj[jt], racc[1][jt], 0, 0, 0);
            __builtin_amdgcn_s_setprio(0);
        }
#pragma unroll
        for (int st = 0; st < 6; st++) raddr[st] = (raddr[st] + 8192) & 32767;
    };

    auto PHASE1 = [&]() {   // source-side pack select + 16 bpermutes
#pragma unroll
        for (int mt = 0; mt < 2; mt++)
#pragma unroll
        for (int rg = 0; rg < 4; rg++) {
            unsigned p01 = pk2bf(racc[mt][0][rg], racc[mt][1][rg]);
            unsigned p12 = pk2bf(racc[mt][1][rg], racc[mt][2][rg]);
            unsigned p23 = pk2bf(racc[mt][2][rg], racc[mt][3][rg]);
            unsigned p34 = pk2bf(racc[mt][3][rg], racc[mt][4][rg]);
            unsigned q1 = slo[rg] ? p01 : p12;
            unsigned q2 = slo[rg] ? p23 : p34;
            g1v[mt][rg] = (unsigned)__builtin_amdgcn_ds_bpermute(slv4[rg], (int)q1);
            g2v[mt][rg] = (unsigned)__builtin_amdgcn_ds_bpermute(slv4[rg], (int)q2);
        }
    };

    auto PHASE2 = [&]() {   // uniform extraction + exp2 + Pb writes
#pragma unroll
        for (int mt = 0; mt < 2; mt++)
#pragma unroll
        for (int rg = 0; rg < 4; rg++) {
            const unsigned a1 = g1v[mt][rg], a2 = g2v[mt][rg];
            const unsigned pb0 = a1 << 16;
            const unsigned pb1 = a1 & 0xffff0000u;
            const unsigned pb2 = a2 << 16;
            const unsigned pb3 = a2 & 0xffff0000u;
            float p0 = ex2(cacc[mt][0][rg] + __uint_as_float(pb0));
            float p1 = ex2(cacc[mt][1][rg] + __uint_as_float(pb1));
            float p2 = ex2(cacc[mt][2][rg] + __uint_as_float(pb2));
            float p3 = ex2(cacc[mt][3][rg] + __uint_as_float(pb3));
            lpart[mt][rg] += (p0 + p1) + (p2 + p3);
            *(uint2*)((char*)Pb + pwoff[rg] + mt * 2048) =
                make_uint2(pk2bf(p0, p1), pk2bf(p2, p3));
        }
    };

    auto PV = [&](int vbuf) {                // PV GEMM on delayed tile
        const char* vbase = (const char*)Vl + vbuf * 8192;
        const char* pbW = (const char*)Pb + w * 4096;
#pragma unroll
        for (int kh = 0; kh < 2; kh++) {
            v8s vf[4];
#pragma unroll
            for (int nt = 0; nt < 4; nt++)
                vf[nt] = *(const v8s*)(vbase + kaddr[kh][nt]);
            v8s pa0 = *(const v8s*)(pbW + (paddr0 ^ (kh << 6)));
            v8s pa1 = *(const v8s*)(pbW + 2048 + (paddr0 ^ (kh << 6)));
            __builtin_amdgcn_s_setprio(1);
#pragma unroll
            for (int nt = 0; nt < 4; nt++)
                o_acc[0][nt] = __builtin_amdgcn_mfma_f32_16x16x32_bf16(
                    pa0, vf[nt], o_acc[0][nt], 0, 0, 0);
#pragma unroll
            for (int nt = 0; nt < 4; nt++)
                o_acc[1][nt] = __builtin_amdgcn_mfma_f32_16x16x32_bf16(
                    pa1, vf[nt], o_acc[1][nt], 0, 0, 0);
            __builtin_amdgcn_s_setprio(0);
        }
    };

    // ================= prologue iteration (t0 = 0) =================
    VMCNT0();                        // prologue loads drained
    SBAR();
    STAGE_K(1);
    QK(0); PHASE1();
    SBAR();                          // B2 (raw): no V reads yet, cheap
    STAGE_V(1);
    PHASE2();

    // ================= main loop (31 iterations) =================
    int cur = 0;
    for (int t0 = 64; t0 < SEQ; t0 += 64) {
        cur ^= 1;
        VMCNT2();                    // K[t]/rel drained; V[t] (newest 2) flies
        SBAR();                      // B1
        STAGE_K(cur ^ 1);            // K[t+1] (full-iter cover)
        QK(cur);
        PHASE1();
        PV(cur ^ 1);                 // PV[t-1]: V in dbuf[cur^1], P in Pb
        SBAR();                      // B2 (raw): V-buffer WAR handoff only
        STAGE_V(cur ^ 1);            // V[t+1]; consumed at PV[t+1] (1.5 iters)
        PHASE2();
    }
    VMCNT0();                        // V[last] landed (everywhere)
    SBAR();
    PV(cur);                         // PV[last]: V[last] in dbuf[cur]

    // ---- epilogue: one row-sum reduction, then normalized store ----
#pragma unroll
    for (int mt = 0; mt < 2; mt++)
#pragma unroll
    for (int rg = 0; rg < 4; rg++) {
        float rs = lpart[mt][rg];
#pragma unroll
        for (int off = 1; off < 16; off <<= 1)
            rs += __shfl_xor(rs, off);
        const float inv = 1.f / rs;
        const int row = s0 + i0 + mt * 16 + quad * 4 + rg;
        const size_t base = ((size_t)b * SEQ + row) * CH + h * HD;
#pragma unroll
        for (int nt = 0; nt < 4; nt++)
            out[base + nt * 16 + l15] = o_acc[mt][nt][rg] * inv;
    }
}

// ---------------------------------------------------------------------------
extern "C" void kernel_launch(void* const* d_in, const int* in_sizes, int n_in,
                              void* d_out, int out_size, void* d_ws, size_t ws_size,
                              hipStream_t stream)
{
    const float* src  = (const float*)d_in[0];
    const float* Wq   = (const float*)d_in[1];
    const float* bq   = (const float*)d_in[2];
    const float* Wk   = (const float*)d_in[3];
    const float* bk   = (const float*)d_in[4];
    const float* Wv   = (const float*)d_in[5];
    const float* bv   = (const float*)d_in[6];
    const float* relk = (const float*)d_in[7];
    float* out = (float*)d_out;

    const size_t nQKV = (size_t)BATCH * SEQ * CH;      // 4 Mi elements
    const size_t nW   = (size_t)CH * CH;               // 1 Mi
    short* qb   = (short*)d_ws;
    short* kb   = qb + nQKV;
    short* vb   = kb + nQKV;
    short* vtb  = vb + nQKV;
    short* xb   = vtb + nQKV;
    short* wqb  = xb + nQKV;
    short* wkb  = wqb + nW;
    short* wvb  = wkb + nW;
    short* relb = wvb + nW;                            // 4095*64 bf16

    cast_all_kernel<<<dim3(512, 1, 5), 256, 0, stream>>>(
        src, Wq, Wk, Wv, relk, xb, wqb, wkb, wvb, relb);

    dim3 gProj(4096 / 128, 1024 / 128, 3);             // (32, 8, 3): x = m-panel
    proj_mfma_kernel<<<gProj, 256, 0, stream>>>(
        xb, wqb, wkb, wvb, bq, bk, bv, qb, kb, vb);

    dim3 gVt(SEQ / 64, BHN);                           // (32, 32)
    vtrans_kernel<<<gVt, 256, 0, stream>>>(vb, vtb);

    dim3 gAttn(BHN, SEQ / 128);                        // (32, 16): x = bh
    attn_mfma_kernel<<<gAttn, 256, 0, stream>>>(qb, kb, vtb, relb, out);
}